// Round 15
// baseline (431.726 us; speedup 1.0000x reference)
//
#include <hip/hip_runtime.h>
#include <hip/hip_bf16.h>
#include <math.h>

// AtnConv (contextual attention) B=2, H=W=64, C=128, k=3.
// R15: R14 base (champion 340.6us) + (a) k_gemm_d re-partitioned: same
// 128x128 block tile, 512 threads / 8 waves (16 rows per wave; ~120 arch
// regs -> 4 waves/SIMD, double residency, SAME block count & HBM traffic) —
// clean occupancy test without R11's traffic confound; (b) gemm_y split-K
// 4->2 (Ypart 8->4MB W+R; 256 blocks = 1/CU).
// Pipeline: Ds = skewed X2·X2^T (split-bf16 MFMA, fp16, Ds[r][(c-r)&4095]);
// invn from exact fp32 pixnorm (fused in split); G = 9-tap diag stencil
// (vertical fp16 reads, XCD-band swizzle); Ps = pooled logits (skewed fp16,
// rounded BEFORE stats) + partial softmax stats -> k_stats_combine;
// A2 = diag stencil of softmax(Ps) (bf16); Y = A2 @ X1 bf16 MFMA split-K=2
// partials -> k_yreduce. Batch-concurrent grids (z=batch).
// Per-slice ws: buf1 [0,32MB) Ds16->Ps16->Ypart(4MB); buf2 [32,64MB):
// X2h/X2l -> G16 -> A2bf; X1T/pmz at +64MB; smalls at +65MB. SLICE=65MB+64KB.
// Lessons: R1 coalescing/R2 DRAM tiling/R7 nt/R13 unskew: neutral or worse.
// R3/R4 fusion loses (LDS). R11 smaller tile loses (traffic). R8 XCD swizzle
// +28. R9 fp16 +53. R10 pool split +38. R12 de-atomic +17. R14 fuse/splitK +4.

constexpr int Hh = 64;
constexpr int Ww = 64;
constexpr int CDIM = 128;
constexpr int LDIM = Hh * Ww;   // 4096

typedef __attribute__((ext_vector_type(8))) short bf16x8;
typedef __attribute__((ext_vector_type(4))) float f32x4;
typedef __attribute__((ext_vector_type(4))) _Float16 f16x4;

// ---- split X2 into bf16 hi/lo parts + fused pixnorm (row sum of squares)
__global__ __launch_bounds__(256)
void k_split(const float* __restrict__ X, __hip_bfloat16* __restrict__ Xh_,
             __hip_bfloat16* __restrict__ Xl_, float* __restrict__ pixn_,
             size_t inStrideF, size_t wsStrideB) {
    const int z = blockIdx.z;
    const float* Xb = X + (size_t)z * inStrideF;
    __hip_bfloat16* Xh = (__hip_bfloat16*)((char*)Xh_ + (size_t)z * wsStrideB);
    __hip_bfloat16* Xl = (__hip_bfloat16*)((char*)Xl_ + (size_t)z * wsStrideB);
    float* pixn = (float*)((char*)pixn_ + (size_t)z * wsStrideB);
    const int i = (blockIdx.x * 256 + threadIdx.x) * 4;
    const float4 v = *(const float4*)(Xb + i);
    __hip_bfloat16 h[4], l[4];
    const float f[4] = {v.x, v.y, v.z, v.w};
    #pragma unroll
    for (int j = 0; j < 4; ++j) {
        h[j] = __float2bfloat16(f[j]);
        l[j] = __float2bfloat16(f[j] - __bfloat162float(h[j]));
    }
    *(ushort4*)(Xh + i) = *(ushort4*)h;
    *(ushort4*)(Xl + i) = *(ushort4*)l;
    // fused pixnorm: 32 lanes cover one 128-col row (4 elems/lane)
    float s = v.x * v.x + v.y * v.y + v.z * v.z + v.w * v.w;
    s += __shfl_xor(s, 1);
    s += __shfl_xor(s, 2);
    s += __shfl_xor(s, 4);
    s += __shfl_xor(s, 8);
    s += __shfl_xor(s, 16);
    if ((threadIdx.x & 31) == 0) pixn[i >> 7] = s;
}

// ---------------- invn[l] = 1/max(sqrt(sum 9-neigh pixn),eps)
__global__ void k_invnorm(const float* __restrict__ pixn_, float* __restrict__ invn_,
                          size_t wsStrideB) {
    const int z = blockIdx.z;
    const float* pixn = (const float*)((const char*)pixn_ + (size_t)z * wsStrideB);
    float* invn = (float*)((char*)invn_ + (size_t)z * wsStrideB);
    const int l = blockIdx.x * 256 + threadIdx.x;
    const int ly = l >> 6, lx = l & 63;
    float s = 0.f;
    #pragma unroll
    for (int ty = -1; ty <= 1; ++ty)
        #pragma unroll
        for (int tx = -1; tx <= 1; ++tx) {
            if ((unsigned)(ly + ty) < 64u && (unsigned)(lx + tx) < 64u)
                s += pixn[l + ty * Ww + tx];
        }
    invn[l] = 1.0f / fmaxf(sqrtf(s), 1e-4f);
}

// -------- Ds = skewed X2·X2^T via 3-term split-bf16 MFMA; fp16 store.
// R15: 512 threads / 8 waves per 128x128 block (16 rows per wave) ->
// ~120 arch regs, 4 waves/SIMD residency. Same blocks, same HBM traffic.
__global__ __launch_bounds__(512)
void k_gemm_d(const __hip_bfloat16* __restrict__ Xh_,
              const __hip_bfloat16* __restrict__ Xl_, _Float16* __restrict__ Ds_,
              size_t wsStrideB) {
    const int z = blockIdx.z;
    const __hip_bfloat16* Xh = (const __hip_bfloat16*)((const char*)Xh_ + (size_t)z * wsStrideB);
    const __hip_bfloat16* Xl = (const __hip_bfloat16*)((const char*)Xl_ + (size_t)z * wsStrideB);
    _Float16* Ds = (_Float16*)((char*)Ds_ + (size_t)z * wsStrideB);
    const int t = threadIdx.x;
    const int wave = t >> 6, lane = t & 63;
    const int quad = lane >> 4, l16 = lane & 15;
    const int bm = blockIdx.x * 128 + wave * 16;
    const int bn = blockIdx.y * 128;
    f32x4 acc[8] = {};
    for (int k0 = 0; k0 < CDIM; k0 += 32) {
        const int kq = k0 + quad * 8;
        const size_t ra = (size_t)(bm + l16) * CDIM + kq;
        const bf16x8 ah = *(const bf16x8*)(Xh + ra);
        const bf16x8 al = *(const bf16x8*)(Xl + ra);
        bf16x8 bh[8], bl[8];
        #pragma unroll
        for (int nf = 0; nf < 8; ++nf) {
            const size_t r = (size_t)(bn + nf * 16 + l16) * CDIM + kq;
            bh[nf] = *(const bf16x8*)(Xh + r);
            bl[nf] = *(const bf16x8*)(Xl + r);
        }
        #pragma unroll
        for (int nf = 0; nf < 8; ++nf) {
            acc[nf] = __builtin_amdgcn_mfma_f32_16x16x32_bf16(ah, bh[nf], acc[nf], 0, 0, 0);
            acc[nf] = __builtin_amdgcn_mfma_f32_16x16x32_bf16(ah, bl[nf], acc[nf], 0, 0, 0);
            acc[nf] = __builtin_amdgcn_mfma_f32_16x16x32_bf16(al, bh[nf], acc[nf], 0, 0, 0);
        }
    }
    #pragma unroll
    for (int nf = 0; nf < 8; ++nf) {
        const int row = bm + quad * 4;
        const int col = bn + nf * 16 + l16;
        #pragma unroll
        for (int r = 0; r < 4; ++r)
            Ds[(size_t)(row + r) * LDIM + ((col - row - r) & (LDIM - 1))] =
                (_Float16)acc[nf][r];
    }
}

// ---- G[x,l] = sum_t D[x+t,l+t] read vertically from skewed fp16 Ds.
// XCD-band swizzle. Thread: 4 diagonals x T=8 rows; f16x4 loads, fp16 store.
__global__ __launch_bounds__(256)
void k_gdiag(const _Float16* __restrict__ Ds_, _Float16* __restrict__ G_,
             size_t wsStrideB) {
    const int z = blockIdx.z;
    const _Float16* Ds = (const _Float16*)((const char*)Ds_ + (size_t)z * wsStrideB);
    _Float16* G = (_Float16*)((char*)G_ + (size_t)z * wsStrideB);
    constexpr int T = 8;
    const int f = blockIdx.x + gridDim.x * blockIdx.y;
    const int swz = (f & 7) * 256 + (f >> 3);
    const int d0 = ((swz & 3) * 256 + threadIdx.x) * 4;
    const int x0 = (swz >> 2) * T;
    const int xyc = x0 >> 6;
    const int xxb = x0 & 63;
    float acc[T][4] = {};
    #pragma unroll
    for (int c = 0; c < 3; ++c) {
        const int bc = c * 64 - 65;          // -65, -1, 63
        const int ty = c - 1;
        if ((unsigned)(xyc + ty) >= 64u) continue;
        float w[T + 2][4];
        #pragma unroll
        for (int u = 0; u < T + 2; ++u) {
            const int r = x0 + bc + u;
            if ((unsigned)r < (unsigned)LDIM) {
                const f16x4 v = *(const f16x4*)(Ds + (size_t)r * LDIM + d0);
                w[u][0] = (float)v.x; w[u][1] = (float)v.y;
                w[u][2] = (float)v.z; w[u][3] = (float)v.w;
            } else {
                w[u][0] = w[u][1] = w[u][2] = w[u][3] = 0.f;
            }
        }
        #pragma unroll
        for (int i = 0; i < T; ++i) {
            const int px = xxb + i;
            const int p  = x0 + i;
            #pragma unroll
            for (int j = 0; j < 4; ++j) {
                const int l  = (p + d0 + j) & (LDIM - 1);
                const int ly = l >> 6, lx = l & 63;
                if ((unsigned)(ly + ty) < 64u) {
                    float s = acc[i][j];
                    if (px > 0 && lx > 0)   s += w[i][j];
                    s += w[i + 1][j];
                    if (px < 63 && lx < 63) s += w[i + 2][j];
                    acc[i][j] = s;
                }
            }
        }
    }
    #pragma unroll
    for (int i = 0; i < T; ++i) {
        const int x = x0 + i;
        const int l0i = (x + d0) & (LDIM - 1);
        union { _Float16 h[4]; unsigned short us[4]; unsigned int ui[2]; } cv;
        #pragma unroll
        for (int j = 0; j < 4; ++j) cv.h[j] = (_Float16)acc[i][j];
        unsigned short* bp = (unsigned short*)(G + (size_t)x * LDIM);
        if (l0i <= LDIM - 4) {
            if (!(l0i & 1)) {
                *(unsigned int*)(bp + l0i)     = cv.ui[0];
                *(unsigned int*)(bp + l0i + 2) = cv.ui[1];
            } else {
                bp[l0i] = cv.us[0];
                *(unsigned int*)(bp + l0i + 1) =
                    (unsigned int)cv.us[1] | ((unsigned int)cv.us[2] << 16);
                bp[l0i + 3] = cv.us[3];
            }
        } else {
            #pragma unroll
            for (int j = 0; j < 4; ++j)
                bp[(l0i + j) & (LDIM - 1)] = cv.us[j];
        }
    }
}

// ------- P[x,l] = (90/cnt)*invn[l]*sum_s G[x+s,l]; one 1024-col chunk per
// block (blockIdx.y = ch). P rounded to fp16 BEFORE stats. Skewed fp16 store.
// Per-(row,ch) partial (m,Z) via wave shfl butterfly -> pmz scratch.
// XCD-band swizzle on blockIdx.x.
__global__ __launch_bounds__(256)
void k_pool_stats(const _Float16* __restrict__ G_, const float* __restrict__ invn_,
                  _Float16* __restrict__ Ps_, float* __restrict__ pmz_,
                  size_t wsStrideB) {
    const int z = blockIdx.z;
    const _Float16* G = (const _Float16*)((const char*)G_ + (size_t)z * wsStrideB);
    const float* invn = (const float*)((const char*)invn_ + (size_t)z * wsStrideB);
    _Float16* Ps = (_Float16*)((char*)Ps_ + (size_t)z * wsStrideB);
    float* pmz = (float*)((char*)pmz_ + (size_t)z * wsStrideB);
    constexpr int T = 8;
    const int f = blockIdx.x;                    // 512 x-blocks
    const int swz = (f & 7) * 64 + (f >> 3);     // XCD k: x0 in [k*512,(k+1)*512)
    const int x0 = swz * T;
    const int ch = blockIdx.y;                   // 1024-col chunk
    const int t  = threadIdx.x;
    const int wave = t >> 6, lane = t & 63;
    const int xyc = x0 >> 6;
    const int xxb = x0 & 63;
    const int cy = 1 + (xyc > 0) + (xyc < 63);
    float sc[T];
    #pragma unroll
    for (int i = 0; i < T; ++i) {
        const int xx = xxb + i;
        sc[i] = 90.0f / (float)(cy * (1 + (xx > 0) + (xx < 63)));
    }
    float m[T], Z[T];

    const int l0 = ch * 1024 + t * 4;
    const f32x4 inl = *(const f32x4*)(invn + l0);
    f32x4 acc[T];
    #pragma unroll
    for (int i = 0; i < T; ++i) acc[i] = (f32x4){0.f, 0.f, 0.f, 0.f};
    #pragma unroll
    for (int c = 0; c < 3; ++c) {
        const int bc = c * 64 - 65;
        const int ty = c - 1;
        if ((unsigned)(xyc + ty) >= 64u) continue;
        f32x4 w[T + 2];
        #pragma unroll
        for (int u = 0; u < T + 2; ++u) {
            const int r = x0 + bc + u;
            if ((unsigned)r < (unsigned)LDIM) {
                const f16x4 v = *(const f16x4*)(G + (size_t)r * LDIM + l0);
                w[u] = (f32x4){(float)v.x, (float)v.y, (float)v.z, (float)v.w};
            } else {
                w[u] = (f32x4){0.f, 0.f, 0.f, 0.f};
            }
        }
        #pragma unroll
        for (int i = 0; i < T; ++i) {
            const int xx = xxb + i;
            if (xx > 0)  acc[i] += w[i];
            acc[i] += w[i + 1];
            if (xx < 63) acc[i] += w[i + 2];
        }
    }
    #pragma unroll
    for (int i = 0; i < T; ++i) {
        const f32x4 p = acc[i] * sc[i] * inl;
        const int x = x0 + i;
        const int c0 = (l0 - x) & (LDIM - 1);
        union { _Float16 h[4]; unsigned short us[4]; unsigned int ui[2]; } cv;
        float pr[4];
        #pragma unroll
        for (int j = 0; j < 4; ++j) {
            cv.h[j] = (_Float16)p[j];
            pr[j] = (float)cv.h[j];
        }
        unsigned short* bp = (unsigned short*)(Ps + (size_t)x * LDIM);
        if (c0 <= LDIM - 4) {
            if (!(c0 & 1)) {
                *(unsigned int*)(bp + c0)     = cv.ui[0];
                *(unsigned int*)(bp + c0 + 2) = cv.ui[1];
            } else {
                bp[c0] = cv.us[0];
                *(unsigned int*)(bp + c0 + 1) =
                    (unsigned int)cv.us[1] | ((unsigned int)cv.us[2] << 16);
                bp[c0 + 3] = cv.us[3];
            }
        } else {
            #pragma unroll
            for (int j = 0; j < 4; ++j)
                bp[(c0 + j) & (LDIM - 1)] = cv.us[j];
        }
        const float mx = fmaxf(fmaxf(pr[0], pr[1]), fmaxf(pr[2], pr[3]));
        m[i] = mx;
        Z[i] = __expf(pr[0] - mx) + __expf(pr[1] - mx)
             + __expf(pr[2] - mx) + __expf(pr[3] - mx);
    }
    // wave butterfly reduction of (m,Z) per row, then 4-wave combine via LDS
    __shared__ float sm[4][T], sz[4][T];
    #pragma unroll
    for (int i = 0; i < T; ++i) {
        float mi = m[i], zi = Z[i];
        #pragma unroll
        for (int s = 1; s < 64; s <<= 1) {
            const float m2 = __shfl_xor(mi, s);
            const float z2 = __shfl_xor(zi, s);
            const float nm = fmaxf(mi, m2);
            zi = zi * __expf(mi - nm) + z2 * __expf(m2 - nm);
            mi = nm;
        }
        if (lane == 0) { sm[wave][i] = mi; sz[wave][i] = zi; }
    }
    __syncthreads();
    if (t < T) {
        float mi = sm[0][t], zi = sz[0][t];
        #pragma unroll
        for (int wv = 1; wv < 4; ++wv) {
            const float m2 = sm[wv][t], z2 = sz[wv][t];
            const float nm = fmaxf(mi, m2);
            zi = zi * __expf(mi - nm) + z2 * __expf(m2 - nm);
            mi = nm;
        }
        pmz[(size_t)ch * LDIM + x0 + t] = mi;                    // partial max
        pmz[(size_t)(4 + ch) * LDIM + x0 + t] = zi;              // partial Z
    }
}

// ---- merge 4 channel-partials -> rowm, rowrz. 16 blocks x 256.
__global__ __launch_bounds__(256)
void k_stats_combine(const float* __restrict__ pmz_, float* __restrict__ rowm_,
                     float* __restrict__ rowrz_, size_t wsStrideB) {
    const int z = blockIdx.z;
    const float* pmz = (const float*)((const char*)pmz_ + (size_t)z * wsStrideB);
    float* rowm = (float*)((char*)rowm_ + (size_t)z * wsStrideB);
    float* rowrz = (float*)((char*)rowrz_ + (size_t)z * wsStrideB);
    const int l = blockIdx.x * 256 + threadIdx.x;
    float mi = pmz[l], zi = pmz[(size_t)4 * LDIM + l];
    #pragma unroll
    for (int ch = 1; ch < 4; ++ch) {
        const float m2 = pmz[(size_t)ch * LDIM + l];
        const float z2 = pmz[(size_t)(4 + ch) * LDIM + l];
        const float nm = fmaxf(mi, m2);
        zi = zi * __expf(mi - nm) + z2 * __expf(m2 - nm);
        mi = nm;
    }
    rowm[l] = mi;
    rowrz[l] = 1.0f / zi;
}

// ---- X1 [4096][128] fp32 -> X1T [128][4096] bf16 (LDS-tiled transpose)
// Runs AFTER k_stats_combine: X1T region doubles as pmz scratch before this.
__global__ __launch_bounds__(256)
void k_x1t(const float* __restrict__ X1, __hip_bfloat16* __restrict__ X1T_,
           size_t inStrideF, size_t wsStrideB) {
    const int z = blockIdx.z;
    const float* X1b = X1 + (size_t)z * inStrideF;
    __hip_bfloat16* X1T = (__hip_bfloat16*)((char*)X1T_ + (size_t)z * wsStrideB);
    __shared__ float tile[32][132];
    const int k0 = blockIdx.x * 32;
    const int t  = threadIdx.x;
    const int kr = t >> 3;
    const int c0 = (t & 7) * 16;
    #pragma unroll
    for (int j = 0; j < 4; ++j) {
        const float4 v = *(const float4*)(X1b + (size_t)(k0 + kr) * CDIM + c0 + 4 * j);
        tile[kr][c0 + 4 * j + 0] = v.x;
        tile[kr][c0 + 4 * j + 1] = v.y;
        tile[kr][c0 + 4 * j + 2] = v.z;
        tile[kr][c0 + 4 * j + 3] = v.w;
    }
    __syncthreads();
    const int c  = t >> 1;
    const int kh = (t & 1) * 16;
    __hip_bfloat16 outv[16];
    #pragma unroll
    for (int j = 0; j < 16; ++j)
        outv[j] = __float2bfloat16(tile[kh + j][c]);
    *(ushort4*)(X1T + (size_t)c * LDIM + k0 + kh)      = *(ushort4*)(outv);
    *(ushort4*)(X1T + (size_t)c * LDIM + k0 + kh + 4)  = *(ushort4*)(outv + 4);
    *(ushort4*)(X1T + (size_t)c * LDIM + k0 + kh + 8)  = *(ushort4*)(outv + 8);
    *(ushort4*)(X1T + (size_t)c * LDIM + k0 + kh + 12) = *(ushort4*)(outv + 12);
}

// ---- A2[p,q] = sum_t exp(P[p+t,q+t]-m)*rz. Reads skewed fp16 Ps vertically.
// XCD-band swizzle matches k_pool_stats' write bands.
__global__ __launch_bounds__(256)
void k_att2(const _Float16* __restrict__ Ps_, const float* __restrict__ rowm_,
            const float* __restrict__ rowrz_, __hip_bfloat16* __restrict__ A2_,
            size_t wsStrideB) {
    const int z = blockIdx.z;
    const _Float16* Ps = (const _Float16*)((const char*)Ps_ + (size_t)z * wsStrideB);
    const float* rowm = (const float*)((const char*)rowm_ + (size_t)z * wsStrideB);
    const float* rowrz = (const float*)((const char*)rowrz_ + (size_t)z * wsStrideB);
    __hip_bfloat16* A2 = (__hip_bfloat16*)((char*)A2_ + (size_t)z * wsStrideB);
    constexpr int T = 8;
    const int f = blockIdx.x + gridDim.x * blockIdx.y;
    const int swz = (f & 7) * 256 + (f >> 3);
    const int d0 = ((swz & 3) * 256 + threadIdx.x) * 4;
    const int p0 = (swz >> 2) * T;
    const int pyc = p0 >> 6;
    const int pxb = p0 & 63;
    float acc[T][4] = {};
    #pragma unroll
    for (int c = 0; c < 3; ++c) {
        const int bc = c * 64 - 65;          // -65, -1, 63
        const int ty = c - 1;
        if ((unsigned)(pyc + ty) >= 64u) continue;
        float e[T + 2][4];
        #pragma unroll
        for (int u = 0; u < T + 2; ++u) {
            const int r = p0 + bc + u;
            if ((unsigned)r < (unsigned)LDIM) {
                const f16x4 w = *(const f16x4*)(Ps + (size_t)r * LDIM + d0);
                const float mr = rowm[r], rzr = rowrz[r];
                e[u][0] = __expf((float)w.x - mr) * rzr;
                e[u][1] = __expf((float)w.y - mr) * rzr;
                e[u][2] = __expf((float)w.z - mr) * rzr;
                e[u][3] = __expf((float)w.w - mr) * rzr;
            } else {
                e[u][0] = e[u][1] = e[u][2] = e[u][3] = 0.f;
            }
        }
        #pragma unroll
        for (int i = 0; i < T; ++i) {
            const int px = pxb + i;
            const int p  = p0 + i;
            #pragma unroll
            for (int j = 0; j < 4; ++j) {
                const int q  = (p + d0 + j) & (LDIM - 1);
                const int qy = q >> 6, qx = q & 63;
                if ((unsigned)(qy + ty) < 64u) {
                    float s = acc[i][j];
                    if (px > 0 && qx > 0)   s += e[i][j];
                    s += e[i + 1][j];
                    if (px < 63 && qx < 63) s += e[i + 2][j];
                    acc[i][j] = s;
                }
            }
        }
    }
    #pragma unroll
    for (int i = 0; i < T; ++i) {
        const int p = p0 + i;
        const int q0i = (p + d0) & (LDIM - 1);
        union { __hip_bfloat16 h[4]; unsigned short us[4]; unsigned int ui[2]; } cv;
        #pragma unroll
        for (int j = 0; j < 4; ++j) cv.h[j] = __float2bfloat16(acc[i][j]);
        unsigned short* bp = (unsigned short*)(A2 + (size_t)p * LDIM);
        if (q0i <= LDIM - 4) {
            if (!(q0i & 1)) {
                *(unsigned int*)(bp + q0i)     = cv.ui[0];
                *(unsigned int*)(bp + q0i + 2) = cv.ui[1];
            } else {
                bp[q0i] = cv.us[0];
                *(unsigned int*)(bp + q0i + 1) =
                    (unsigned int)cv.us[1] | ((unsigned int)cv.us[2] << 16);
                bp[q0i + 3] = cv.us[3];
            }
        } else {
            #pragma unroll
            for (int j = 0; j < 4; ++j)
                bp[(q0i + j) & (LDIM - 1)] = cv.us[j];
        }
    }
}

// ---------- Ypart[slice] = A2[.,kc:kc+2048] @ X1T[.,kc:kc+2048]^T (split-K=2)
__global__ __launch_bounds__(256)
void k_gemm_y(const __hip_bfloat16* __restrict__ A2b_,
              const __hip_bfloat16* __restrict__ X1T_, float* __restrict__ Ypart_,
              size_t wsStrideB) {
    const int z = blockIdx.z;
    const __hip_bfloat16* A2b = (const __hip_bfloat16*)((const char*)A2b_ + (size_t)z * wsStrideB);
    const __hip_bfloat16* X1T = (const __hip_bfloat16*)((const char*)X1T_ + (size_t)z * wsStrideB);
    float* Ypart = (float*)((char*)Ypart_ + (size_t)z * wsStrideB)
                 + (size_t)blockIdx.y * LDIM * CDIM;
    const int t = threadIdx.x;
    const int wave = t >> 6, lane = t & 63;
    const int quad = lane >> 4, l16 = lane & 15;
    const int bm = blockIdx.x * 128 + wave * 32;
    const int kc = blockIdx.y * 2048;
    f32x4 acc[2][8] = {};
    for (int ks = 0; ks < 2048; ks += 32) {
        const int kq = kc + ks + quad * 8;
        bf16x8 a[2], b[8];
        #pragma unroll
        for (int mi = 0; mi < 2; ++mi)
            a[mi] = *(const bf16x8*)(A2b + (size_t)(bm + mi * 16 + l16) * LDIM + kq);
        #pragma unroll
        for (int nf = 0; nf < 8; ++nf)
            b[nf] = *(const bf16x8*)(X1T + (size_t)(nf * 16 + l16) * LDIM + kq);
        #pragma unroll
        for (int mi = 0; mi < 2; ++mi)
            #pragma unroll
            for (int nf = 0; nf < 8; ++nf)
                acc[mi][nf] = __builtin_amdgcn_mfma_f32_16x16x32_bf16(a[mi], b[nf], acc[mi][nf], 0, 0, 0);
    }
    #pragma unroll
    for (int mi = 0; mi < 2; ++mi)
        #pragma unroll
        for (int nf = 0; nf < 8; ++nf)
            #pragma unroll
            for (int r = 0; r < 4; ++r)
                Ypart[(size_t)(bm + mi * 16 + quad * 4 + r) * CDIM + nf * 16 + l16] =
                    acc[mi][nf][r];
}

// ---------- Y = sum of 2 K-slices of Ypart (float4 streams)
__global__ __launch_bounds__(256)
void k_yreduce(const float* __restrict__ Ypart_, float* __restrict__ Y_,
               size_t wsStrideB, size_t outStrideF) {
    const int z = blockIdx.z;
    const float* Ypart = (const float*)((const char*)Ypart_ + (size_t)z * wsStrideB);
    float* Y = Y_ + (size_t)z * outStrideF;
    const size_t i = ((size_t)blockIdx.x * 256 + threadIdx.x) * 4;
    f32x4 s = *(const f32x4*)(Ypart + i);
    s += *(const f32x4*)(Ypart + (size_t)LDIM * CDIM + i);
    *(f32x4*)(Y + i) = s;
}

extern "C" void kernel_launch(void* const* d_in, const int* in_sizes, int n_in,
                              void* d_out, int out_size, void* d_ws, size_t ws_size,
                              hipStream_t stream) {
    const float* x1 = (const float*)d_in[0];
    const float* x2 = (const float*)d_in[1];
    float* out = (float*)d_out;

    const size_t MATB = (size_t)LDIM * LDIM * sizeof(float);   // 64 MB
    const size_t HMATB = MATB / 2;                             // 32 MB (fp16 mat)
    const size_t SMALLB = (size_t)64 * 1024;
    const size_t SLICE = HMATB + HMATB + (size_t)LDIM * CDIM * sizeof(__hip_bfloat16) + SMALLB;

    const int B = in_sizes[0] / (LDIM * CDIM);
    const size_t inStrideF = (size_t)LDIM * CDIM;
    const bool concurrent = ((size_t)B * SLICE <= ws_size);

    // no d_out memset needed — k_yreduce overwrites Y entirely.

    const int NB = concurrent ? B : 1;         // grid.z
    const int NL = concurrent ? 1 : B;         // host loop count
    const size_t wsStrideB = concurrent ? SLICE : 0;

    for (int b = 0; b < NL; ++b) {
        char* ws = (char*)d_ws;
        _Float16* Dsh = (_Float16*)ws;                       // buf1: Ds16 -> Ps16 -> Ypart
        _Float16* Psh = (_Float16*)ws;
        float* Ypart = (float*)ws;                           // 4MB, after att2
        char* buf2c = ws + HMATB;                            // 33 MB multi-use
        _Float16* Gh = (_Float16*)buf2c;                     // 32 MB
        __hip_bfloat16* X2h = (__hip_bfloat16*)buf2c;                    // 1 MB
        __hip_bfloat16* X2l = (__hip_bfloat16*)(buf2c + (size_t)LDIM * CDIM * 2);
        __hip_bfloat16* A2b = (__hip_bfloat16*)buf2c;                    // 32 MB
        __hip_bfloat16* X1T = (__hip_bfloat16*)(buf2c + HMATB);          // 1 MB
        float* pmz = (float*)(buf2c + HMATB);   // 128KB scratch, dead before x1t
        float* invn  = (float*)(ws + HMATB + HMATB + (size_t)LDIM * CDIM * sizeof(__hip_bfloat16));
        float* rowm  = invn + LDIM;
        float* rowrz = rowm + LDIM;
        float* pixn  = rowrz + LDIM;

        const float* X2b_ = x2 + (size_t)b * inStrideF;
        const float* X1b_ = x1 + (size_t)b * inStrideF;
        float* Yb = out + (size_t)b * inStrideF;
        const size_t inS = concurrent ? inStrideF : 0;
        const size_t outS = concurrent ? inStrideF : 0;

        k_split        <<<dim3(LDIM * CDIM / 1024, 1, NB), 256, 0, stream>>>(X2b_, X2h, X2l, pixn, inS, wsStrideB);
        k_invnorm      <<<dim3(LDIM / 256, 1, NB), 256, 0, stream>>>(pixn, invn, wsStrideB);
        k_gemm_d       <<<dim3(LDIM / 128, LDIM / 128, NB), 512, 0, stream>>>(X2h, X2l, Dsh, wsStrideB);
        k_gdiag        <<<dim3(LDIM / 1024, LDIM / 8, NB), 256, 0, stream>>>(Dsh, Gh, wsStrideB);
        k_pool_stats   <<<dim3(LDIM / 8, 4, NB), 256, 0, stream>>>(Gh, invn, Psh, pmz, wsStrideB);
        k_stats_combine<<<dim3(LDIM / 256, 1, NB), 256, 0, stream>>>(pmz, rowm, rowrz, wsStrideB);
        k_x1t          <<<dim3(LDIM / 32, 1, NB), 256, 0, stream>>>(X1b_, X1T, inS, wsStrideB);
        k_att2         <<<dim3(LDIM / 1024, LDIM / 8, NB), 256, 0, stream>>>(Psh, rowm, rowrz, A2b, wsStrideB);
        k_gemm_y       <<<dim3(LDIM / 128, 2, NB), 256, 0, stream>>>(A2b, X1T, Ypart, wsStrideB);
        k_yreduce      <<<dim3(LDIM * CDIM / 1024, 1, NB), 256, 0, stream>>>(Ypart, Yb, wsStrideB, outS);
    }
}

// Round 16
// 365.311 us; speedup vs baseline: 1.1818x; 1.1818x over previous
//
#include <hip/hip_runtime.h>
#include <hip/hip_bf16.h>
#include <math.h>

// AtnConv (contextual attention) B=2, H=W=64, C=128, k=3.
// R16: exact R14 config restored (champion 340.6us) — gemm_d 256-thr 2x8
// register tile (R15's 8-wave re-partition REGRESSED 88->140us at 41% occ:
// perf tracks MFMA-per-load amortization, NOT occupancy; R11+R15 close the
// book both directions), gemm_y split-K=4 (R15's K=2 left 128 blocks for
// 256 CUs). New: k_stats_combine folded into k_att2 (reads pmz partials,
// merges inline — bit-identical; -1 launch). ORDER: att2 BEFORE x1t now
// (X1T overwrites pmz region).
// Pipeline: Ds = skewed X2·X2^T (split-bf16 MFMA, fp16, Ds[r][(c-r)&4095]);
// invn from exact fp32 pixnorm (fused in split); G = 9-tap diag stencil
// (vertical fp16 reads, XCD-band swizzle); Ps = pooled logits (skewed fp16,
// rounded BEFORE stats) + partial softmax stats (blockIdx.y=ch, wave
// butterfly) -> pmz; A2 = diag stencil of softmax(Ps) (bf16, inline stats
// merge); Y = A2 @ X1 bf16 MFMA split-K=4 partials -> k_yreduce.
// Batch-concurrent grids (z=batch).
// Per-slice ws: buf1 [0,32MB) Ds16->Ps16->Ypart(8MB); buf2 [32,64MB):
// X2h/X2l -> G16 -> A2bf; X1T/pmz at +64MB; smalls at +65MB. SLICE=65MB+64KB.
// Lessons: R1 coalescing/R2 DRAM tiling/R7 nt/R13 unskew: neutral/worse.
// R3/R4 fusion loses (LDS). R11+R15 gemm_d re-tiling loses both ways.
// R8 XCD swizzle +28. R9 fp16 +53. R10 pool split +38. R12 de-atomic +17.
// R14 fuse/splitK4 +4.

constexpr int Hh = 64;
constexpr int Ww = 64;
constexpr int CDIM = 128;
constexpr int LDIM = Hh * Ww;   // 4096

typedef __attribute__((ext_vector_type(8))) short bf16x8;
typedef __attribute__((ext_vector_type(4))) float f32x4;
typedef __attribute__((ext_vector_type(4))) _Float16 f16x4;

// ---- split X2 into bf16 hi/lo parts + fused pixnorm (row sum of squares)
__global__ __launch_bounds__(256)
void k_split(const float* __restrict__ X, __hip_bfloat16* __restrict__ Xh_,
             __hip_bfloat16* __restrict__ Xl_, float* __restrict__ pixn_,
             size_t inStrideF, size_t wsStrideB) {
    const int z = blockIdx.z;
    const float* Xb = X + (size_t)z * inStrideF;
    __hip_bfloat16* Xh = (__hip_bfloat16*)((char*)Xh_ + (size_t)z * wsStrideB);
    __hip_bfloat16* Xl = (__hip_bfloat16*)((char*)Xl_ + (size_t)z * wsStrideB);
    float* pixn = (float*)((char*)pixn_ + (size_t)z * wsStrideB);
    const int i = (blockIdx.x * 256 + threadIdx.x) * 4;
    const float4 v = *(const float4*)(Xb + i);
    __hip_bfloat16 h[4], l[4];
    const float f[4] = {v.x, v.y, v.z, v.w};
    #pragma unroll
    for (int j = 0; j < 4; ++j) {
        h[j] = __float2bfloat16(f[j]);
        l[j] = __float2bfloat16(f[j] - __bfloat162float(h[j]));
    }
    *(ushort4*)(Xh + i) = *(ushort4*)h;
    *(ushort4*)(Xl + i) = *(ushort4*)l;
    // fused pixnorm: 32 lanes cover one 128-col row (4 elems/lane)
    float s = v.x * v.x + v.y * v.y + v.z * v.z + v.w * v.w;
    s += __shfl_xor(s, 1);
    s += __shfl_xor(s, 2);
    s += __shfl_xor(s, 4);
    s += __shfl_xor(s, 8);
    s += __shfl_xor(s, 16);
    if ((threadIdx.x & 31) == 0) pixn[i >> 7] = s;
}

// ---------------- invn[l] = 1/max(sqrt(sum 9-neigh pixn),eps)
__global__ void k_invnorm(const float* __restrict__ pixn_, float* __restrict__ invn_,
                          size_t wsStrideB) {
    const int z = blockIdx.z;
    const float* pixn = (const float*)((const char*)pixn_ + (size_t)z * wsStrideB);
    float* invn = (float*)((char*)invn_ + (size_t)z * wsStrideB);
    const int l = blockIdx.x * 256 + threadIdx.x;
    const int ly = l >> 6, lx = l & 63;
    float s = 0.f;
    #pragma unroll
    for (int ty = -1; ty <= 1; ++ty)
        #pragma unroll
        for (int tx = -1; tx <= 1; ++tx) {
            if ((unsigned)(ly + ty) < 64u && (unsigned)(lx + tx) < 64u)
                s += pixn[l + ty * Ww + tx];
        }
    invn[l] = 1.0f / fmaxf(sqrtf(s), 1e-4f);
}

// -------- Ds = skewed X2·X2^T via 3-term split-bf16 MFMA; fp16 store.
// R14 config: 256 threads, 4 waves, 2x8 register tile (do not re-tile:
// R11 smaller-B and R15 8-wave both regressed).
__global__ __launch_bounds__(256)
void k_gemm_d(const __hip_bfloat16* __restrict__ Xh_,
              const __hip_bfloat16* __restrict__ Xl_, _Float16* __restrict__ Ds_,
              size_t wsStrideB) {
    const int z = blockIdx.z;
    const __hip_bfloat16* Xh = (const __hip_bfloat16*)((const char*)Xh_ + (size_t)z * wsStrideB);
    const __hip_bfloat16* Xl = (const __hip_bfloat16*)((const char*)Xl_ + (size_t)z * wsStrideB);
    _Float16* Ds = (_Float16*)((char*)Ds_ + (size_t)z * wsStrideB);
    const int t = threadIdx.x;
    const int wave = t >> 6, lane = t & 63;
    const int quad = lane >> 4, l16 = lane & 15;
    const int bm = blockIdx.x * 128 + wave * 32;
    const int bn = blockIdx.y * 128;
    f32x4 acc[2][8] = {};
    for (int k0 = 0; k0 < CDIM; k0 += 32) {
        const int kq = k0 + quad * 8;
        bf16x8 ah[2], al[2], bh[8], bl[8];
        #pragma unroll
        for (int mi = 0; mi < 2; ++mi) {
            const size_t r = (size_t)(bm + mi * 16 + l16) * CDIM + kq;
            ah[mi] = *(const bf16x8*)(Xh + r);
            al[mi] = *(const bf16x8*)(Xl + r);
        }
        #pragma unroll
        for (int nf = 0; nf < 8; ++nf) {
            const size_t r = (size_t)(bn + nf * 16 + l16) * CDIM + kq;
            bh[nf] = *(const bf16x8*)(Xh + r);
            bl[nf] = *(const bf16x8*)(Xl + r);
        }
        #pragma unroll
        for (int mi = 0; mi < 2; ++mi)
            #pragma unroll
            for (int nf = 0; nf < 8; ++nf) {
                acc[mi][nf] = __builtin_amdgcn_mfma_f32_16x16x32_bf16(ah[mi], bh[nf], acc[mi][nf], 0, 0, 0);
                acc[mi][nf] = __builtin_amdgcn_mfma_f32_16x16x32_bf16(ah[mi], bl[nf], acc[mi][nf], 0, 0, 0);
                acc[mi][nf] = __builtin_amdgcn_mfma_f32_16x16x32_bf16(al[mi], bh[nf], acc[mi][nf], 0, 0, 0);
            }
    }
    #pragma unroll
    for (int mi = 0; mi < 2; ++mi)
        #pragma unroll
        for (int nf = 0; nf < 8; ++nf) {
            const int row = bm + mi * 16 + quad * 4;
            const int col = bn + nf * 16 + l16;
            #pragma unroll
            for (int r = 0; r < 4; ++r)
                Ds[(size_t)(row + r) * LDIM + ((col - row - r) & (LDIM - 1))] =
                    (_Float16)acc[mi][nf][r];
        }
}

// ---- G[x,l] = sum_t D[x+t,l+t] read vertically from skewed fp16 Ds.
// XCD-band swizzle. Thread: 4 diagonals x T=8 rows; f16x4 loads, fp16 store.
__global__ __launch_bounds__(256)
void k_gdiag(const _Float16* __restrict__ Ds_, _Float16* __restrict__ G_,
             size_t wsStrideB) {
    const int z = blockIdx.z;
    const _Float16* Ds = (const _Float16*)((const char*)Ds_ + (size_t)z * wsStrideB);
    _Float16* G = (_Float16*)((char*)G_ + (size_t)z * wsStrideB);
    constexpr int T = 8;
    const int f = blockIdx.x + gridDim.x * blockIdx.y;
    const int swz = (f & 7) * 256 + (f >> 3);
    const int d0 = ((swz & 3) * 256 + threadIdx.x) * 4;
    const int x0 = (swz >> 2) * T;
    const int xyc = x0 >> 6;
    const int xxb = x0 & 63;
    float acc[T][4] = {};
    #pragma unroll
    for (int c = 0; c < 3; ++c) {
        const int bc = c * 64 - 65;          // -65, -1, 63
        const int ty = c - 1;
        if ((unsigned)(xyc + ty) >= 64u) continue;
        float w[T + 2][4];
        #pragma unroll
        for (int u = 0; u < T + 2; ++u) {
            const int r = x0 + bc + u;
            if ((unsigned)r < (unsigned)LDIM) {
                const f16x4 v = *(const f16x4*)(Ds + (size_t)r * LDIM + d0);
                w[u][0] = (float)v.x; w[u][1] = (float)v.y;
                w[u][2] = (float)v.z; w[u][3] = (float)v.w;
            } else {
                w[u][0] = w[u][1] = w[u][2] = w[u][3] = 0.f;
            }
        }
        #pragma unroll
        for (int i = 0; i < T; ++i) {
            const int px = xxb + i;
            const int p  = x0 + i;
            #pragma unroll
            for (int j = 0; j < 4; ++j) {
                const int l  = (p + d0 + j) & (LDIM - 1);
                const int ly = l >> 6, lx = l & 63;
                if ((unsigned)(ly + ty) < 64u) {
                    float s = acc[i][j];
                    if (px > 0 && lx > 0)   s += w[i][j];
                    s += w[i + 1][j];
                    if (px < 63 && lx < 63) s += w[i + 2][j];
                    acc[i][j] = s;
                }
            }
        }
    }
    #pragma unroll
    for (int i = 0; i < T; ++i) {
        const int x = x0 + i;
        const int l0i = (x + d0) & (LDIM - 1);
        union { _Float16 h[4]; unsigned short us[4]; unsigned int ui[2]; } cv;
        #pragma unroll
        for (int j = 0; j < 4; ++j) cv.h[j] = (_Float16)acc[i][j];
        unsigned short* bp = (unsigned short*)(G + (size_t)x * LDIM);
        if (l0i <= LDIM - 4) {
            if (!(l0i & 1)) {
                *(unsigned int*)(bp + l0i)     = cv.ui[0];
                *(unsigned int*)(bp + l0i + 2) = cv.ui[1];
            } else {
                bp[l0i] = cv.us[0];
                *(unsigned int*)(bp + l0i + 1) =
                    (unsigned int)cv.us[1] | ((unsigned int)cv.us[2] << 16);
                bp[l0i + 3] = cv.us[3];
            }
        } else {
            #pragma unroll
            for (int j = 0; j < 4; ++j)
                bp[(l0i + j) & (LDIM - 1)] = cv.us[j];
        }
    }
}

// ------- P[x,l] = (90/cnt)*invn[l]*sum_s G[x+s,l]; one 1024-col chunk per
// block (blockIdx.y = ch). P rounded to fp16 BEFORE stats. Skewed fp16 store.
// Per-(row,ch) partial (m,Z) via wave shfl butterfly -> pmz scratch.
// XCD-band swizzle on blockIdx.x.
__global__ __launch_bounds__(256)
void k_pool_stats(const _Float16* __restrict__ G_, const float* __restrict__ invn_,
                  _Float16* __restrict__ Ps_, float* __restrict__ pmz_,
                  size_t wsStrideB) {
    const int z = blockIdx.z;
    const _Float16* G = (const _Float16*)((const char*)G_ + (size_t)z * wsStrideB);
    const float* invn = (const float*)((const char*)invn_ + (size_t)z * wsStrideB);
    _Float16* Ps = (_Float16*)((char*)Ps_ + (size_t)z * wsStrideB);
    float* pmz = (float*)((char*)pmz_ + (size_t)z * wsStrideB);
    constexpr int T = 8;
    const int f = blockIdx.x;                    // 512 x-blocks
    const int swz = (f & 7) * 64 + (f >> 3);     // XCD k: x0 in [k*512,(k+1)*512)
    const int x0 = swz * T;
    const int ch = blockIdx.y;                   // 1024-col chunk
    const int t  = threadIdx.x;
    const int wave = t >> 6, lane = t & 63;
    const int xyc = x0 >> 6;
    const int xxb = x0 & 63;
    const int cy = 1 + (xyc > 0) + (xyc < 63);
    float sc[T];
    #pragma unroll
    for (int i = 0; i < T; ++i) {
        const int xx = xxb + i;
        sc[i] = 90.0f / (float)(cy * (1 + (xx > 0) + (xx < 63)));
    }
    float m[T], Z[T];

    const int l0 = ch * 1024 + t * 4;
    const f32x4 inl = *(const f32x4*)(invn + l0);
    f32x4 acc[T];
    #pragma unroll
    for (int i = 0; i < T; ++i) acc[i] = (f32x4){0.f, 0.f, 0.f, 0.f};
    #pragma unroll
    for (int c = 0; c < 3; ++c) {
        const int bc = c * 64 - 65;
        const int ty = c - 1;
        if ((unsigned)(xyc + ty) >= 64u) continue;
        f32x4 w[T + 2];
        #pragma unroll
        for (int u = 0; u < T + 2; ++u) {
            const int r = x0 + bc + u;
            if ((unsigned)r < (unsigned)LDIM) {
                const f16x4 v = *(const f16x4*)(G + (size_t)r * LDIM + l0);
                w[u] = (f32x4){(float)v.x, (float)v.y, (float)v.z, (float)v.w};
            } else {
                w[u] = (f32x4){0.f, 0.f, 0.f, 0.f};
            }
        }
        #pragma unroll
        for (int i = 0; i < T; ++i) {
            const int xx = xxb + i;
            if (xx > 0)  acc[i] += w[i];
            acc[i] += w[i + 1];
            if (xx < 63) acc[i] += w[i + 2];
        }
    }
    #pragma unroll
    for (int i = 0; i < T; ++i) {
        const f32x4 p = acc[i] * sc[i] * inl;
        const int x = x0 + i;
        const int c0 = (l0 - x) & (LDIM - 1);
        union { _Float16 h[4]; unsigned short us[4]; unsigned int ui[2]; } cv;
        float pr[4];
        #pragma unroll
        for (int j = 0; j < 4; ++j) {
            cv.h[j] = (_Float16)p[j];
            pr[j] = (float)cv.h[j];
        }
        unsigned short* bp = (unsigned short*)(Ps + (size_t)x * LDIM);
        if (c0 <= LDIM - 4) {
            if (!(c0 & 1)) {
                *(unsigned int*)(bp + c0)     = cv.ui[0];
                *(unsigned int*)(bp + c0 + 2) = cv.ui[1];
            } else {
                bp[c0] = cv.us[0];
                *(unsigned int*)(bp + c0 + 1) =
                    (unsigned int)cv.us[1] | ((unsigned int)cv.us[2] << 16);
                bp[c0 + 3] = cv.us[3];
            }
        } else {
            #pragma unroll
            for (int j = 0; j < 4; ++j)
                bp[(c0 + j) & (LDIM - 1)] = cv.us[j];
        }
        const float mx = fmaxf(fmaxf(pr[0], pr[1]), fmaxf(pr[2], pr[3]));
        m[i] = mx;
        Z[i] = __expf(pr[0] - mx) + __expf(pr[1] - mx)
             + __expf(pr[2] - mx) + __expf(pr[3] - mx);
    }
    // wave butterfly reduction of (m,Z) per row, then 4-wave combine via LDS
    __shared__ float sm[4][T], sz[4][T];
    #pragma unroll
    for (int i = 0; i < T; ++i) {
        float mi = m[i], zi = Z[i];
        #pragma unroll
        for (int s = 1; s < 64; s <<= 1) {
            const float m2 = __shfl_xor(mi, s);
            const float z2 = __shfl_xor(zi, s);
            const float nm = fmaxf(mi, m2);
            zi = zi * __expf(mi - nm) + z2 * __expf(m2 - nm);
            mi = nm;
        }
        if (lane == 0) { sm[wave][i] = mi; sz[wave][i] = zi; }
    }
    __syncthreads();
    if (t < T) {
        float mi = sm[0][t], zi = sz[0][t];
        #pragma unroll
        for (int wv = 1; wv < 4; ++wv) {
            const float m2 = sm[wv][t], z2 = sz[wv][t];
            const float nm = fmaxf(mi, m2);
            zi = zi * __expf(mi - nm) + z2 * __expf(m2 - nm);
            mi = nm;
        }
        pmz[(size_t)ch * LDIM + x0 + t] = mi;                    // partial max
        pmz[(size_t)(4 + ch) * LDIM + x0 + t] = zi;              // partial Z
    }
}

// ---- A2[p,q] = sum_t exp(P[p+t,q+t]-m)*rz. Reads skewed fp16 Ps vertically.
// Row stats merged INLINE from pmz partials (bit-identical to old combine).
// RUNS BEFORE k_x1t (X1T overwrites the pmz region). XCD-band swizzle.
__global__ __launch_bounds__(256)
void k_att2(const _Float16* __restrict__ Ps_, const float* __restrict__ pmz_,
            __hip_bfloat16* __restrict__ A2_, size_t wsStrideB) {
    const int z = blockIdx.z;
    const _Float16* Ps = (const _Float16*)((const char*)Ps_ + (size_t)z * wsStrideB);
    const float* pmz = (const float*)((const char*)pmz_ + (size_t)z * wsStrideB);
    __hip_bfloat16* A2 = (__hip_bfloat16*)((char*)A2_ + (size_t)z * wsStrideB);
    constexpr int T = 8;
    const int f = blockIdx.x + gridDim.x * blockIdx.y;
    const int swz = (f & 7) * 256 + (f >> 3);
    const int d0 = ((swz & 3) * 256 + threadIdx.x) * 4;
    const int p0 = (swz >> 2) * T;
    const int pyc = p0 >> 6;
    const int pxb = p0 & 63;
    float acc[T][4] = {};
    #pragma unroll
    for (int c = 0; c < 3; ++c) {
        const int bc = c * 64 - 65;          // -65, -1, 63
        const int ty = c - 1;
        if ((unsigned)(pyc + ty) >= 64u) continue;
        float e[T + 2][4];
        #pragma unroll
        for (int u = 0; u < T + 2; ++u) {
            const int r = p0 + bc + u;
            if ((unsigned)r < (unsigned)LDIM) {
                // inline stats merge (same order as old k_stats_combine)
                float mr = pmz[r], zr = pmz[(size_t)4 * LDIM + r];
                #pragma unroll
                for (int ch = 1; ch < 4; ++ch) {
                    const float m2 = pmz[(size_t)ch * LDIM + r];
                    const float z2 = pmz[(size_t)(4 + ch) * LDIM + r];
                    const float nm = fmaxf(mr, m2);
                    zr = zr * __expf(mr - nm) + z2 * __expf(m2 - nm);
                    mr = nm;
                }
                const float rzr = 1.0f / zr;
                const f16x4 w = *(const f16x4*)(Ps + (size_t)r * LDIM + d0);
                e[u][0] = __expf((float)w.x - mr) * rzr;
                e[u][1] = __expf((float)w.y - mr) * rzr;
                e[u][2] = __expf((float)w.z - mr) * rzr;
                e[u][3] = __expf((float)w.w - mr) * rzr;
            } else {
                e[u][0] = e[u][1] = e[u][2] = e[u][3] = 0.f;
            }
        }
        #pragma unroll
        for (int i = 0; i < T; ++i) {
            const int px = pxb + i;
            const int p  = p0 + i;
            #pragma unroll
            for (int j = 0; j < 4; ++j) {
                const int q  = (p + d0 + j) & (LDIM - 1);
                const int qy = q >> 6, qx = q & 63;
                if ((unsigned)(qy + ty) < 64u) {
                    float s = acc[i][j];
                    if (px > 0 && qx > 0)   s += e[i][j];
                    s += e[i + 1][j];
                    if (px < 63 && qx < 63) s += e[i + 2][j];
                    acc[i][j] = s;
                }
            }
        }
    }
    #pragma unroll
    for (int i = 0; i < T; ++i) {
        const int p = p0 + i;
        const int q0i = (p + d0) & (LDIM - 1);
        union { __hip_bfloat16 h[4]; unsigned short us[4]; unsigned int ui[2]; } cv;
        #pragma unroll
        for (int j = 0; j < 4; ++j) cv.h[j] = __float2bfloat16(acc[i][j]);
        unsigned short* bp = (unsigned short*)(A2 + (size_t)p * LDIM);
        if (q0i <= LDIM - 4) {
            if (!(q0i & 1)) {
                *(unsigned int*)(bp + q0i)     = cv.ui[0];
                *(unsigned int*)(bp + q0i + 2) = cv.ui[1];
            } else {
                bp[q0i] = cv.us[0];
                *(unsigned int*)(bp + q0i + 1) =
                    (unsigned int)cv.us[1] | ((unsigned int)cv.us[2] << 16);
                bp[q0i + 3] = cv.us[3];
            }
        } else {
            #pragma unroll
            for (int j = 0; j < 4; ++j)
                bp[(q0i + j) & (LDIM - 1)] = cv.us[j];
        }
    }
}

// ---- X1 [4096][128] fp32 -> X1T [128][4096] bf16 (LDS-tiled transpose)
// RUNS AFTER k_att2: X1T region overlaps pmz scratch (consumed by att2).
__global__ __launch_bounds__(256)
void k_x1t(const float* __restrict__ X1, __hip_bfloat16* __restrict__ X1T_,
           size_t inStrideF, size_t wsStrideB) {
    const int z = blockIdx.z;
    const float* X1b = X1 + (size_t)z * inStrideF;
    __hip_bfloat16* X1T = (__hip_bfloat16*)((char*)X1T_ + (size_t)z * wsStrideB);
    __shared__ float tile[32][132];
    const int k0 = blockIdx.x * 32;
    const int t  = threadIdx.x;
    const int kr = t >> 3;
    const int c0 = (t & 7) * 16;
    #pragma unroll
    for (int j = 0; j < 4; ++j) {
        const float4 v = *(const float4*)(X1b + (size_t)(k0 + kr) * CDIM + c0 + 4 * j);
        tile[kr][c0 + 4 * j + 0] = v.x;
        tile[kr][c0 + 4 * j + 1] = v.y;
        tile[kr][c0 + 4 * j + 2] = v.z;
        tile[kr][c0 + 4 * j + 3] = v.w;
    }
    __syncthreads();
    const int c  = t >> 1;
    const int kh = (t & 1) * 16;
    __hip_bfloat16 outv[16];
    #pragma unroll
    for (int j = 0; j < 16; ++j)
        outv[j] = __float2bfloat16(tile[kh + j][c]);
    *(ushort4*)(X1T + (size_t)c * LDIM + k0 + kh)      = *(ushort4*)(outv);
    *(ushort4*)(X1T + (size_t)c * LDIM + k0 + kh + 4)  = *(ushort4*)(outv + 4);
    *(ushort4*)(X1T + (size_t)c * LDIM + k0 + kh + 8)  = *(ushort4*)(outv + 8);
    *(ushort4*)(X1T + (size_t)c * LDIM + k0 + kh + 12) = *(ushort4*)(outv + 12);
}

// ---------- Ypart[slice] = A2[.,kc:kc+1024] @ X1T[.,kc:kc+1024]^T (split-K=4)
__global__ __launch_bounds__(256)
void k_gemm_y(const __hip_bfloat16* __restrict__ A2b_,
              const __hip_bfloat16* __restrict__ X1T_, float* __restrict__ Ypart_,
              size_t wsStrideB) {
    const int z = blockIdx.z;
    const __hip_bfloat16* A2b = (const __hip_bfloat16*)((const char*)A2b_ + (size_t)z * wsStrideB);
    const __hip_bfloat16* X1T = (const __hip_bfloat16*)((const char*)X1T_ + (size_t)z * wsStrideB);
    float* Ypart = (float*)((char*)Ypart_ + (size_t)z * wsStrideB)
                 + (size_t)blockIdx.y * LDIM * CDIM;
    const int t = threadIdx.x;
    const int wave = t >> 6, lane = t & 63;
    const int quad = lane >> 4, l16 = lane & 15;
    const int bm = blockIdx.x * 128 + wave * 32;
    const int kc = blockIdx.y * 1024;
    f32x4 acc[2][8] = {};
    for (int ks = 0; ks < 1024; ks += 32) {
        const int kq = kc + ks + quad * 8;
        bf16x8 a[2], b[8];
        #pragma unroll
        for (int mi = 0; mi < 2; ++mi)
            a[mi] = *(const bf16x8*)(A2b + (size_t)(bm + mi * 16 + l16) * LDIM + kq);
        #pragma unroll
        for (int nf = 0; nf < 8; ++nf)
            b[nf] = *(const bf16x8*)(X1T + (size_t)(nf * 16 + l16) * LDIM + kq);
        #pragma unroll
        for (int mi = 0; mi < 2; ++mi)
            #pragma unroll
            for (int nf = 0; nf < 8; ++nf)
                acc[mi][nf] = __builtin_amdgcn_mfma_f32_16x16x32_bf16(a[mi], b[nf], acc[mi][nf], 0, 0, 0);
    }
    #pragma unroll
    for (int mi = 0; mi < 2; ++mi)
        #pragma unroll
        for (int nf = 0; nf < 8; ++nf)
            #pragma unroll
            for (int r = 0; r < 4; ++r)
                Ypart[(size_t)(bm + mi * 16 + quad * 4 + r) * CDIM + nf * 16 + l16] =
                    acc[mi][nf][r];
}

// ---------- Y = sum of 4 K-slices of Ypart (float4 streams)
__global__ __launch_bounds__(256)
void k_yreduce(const float* __restrict__ Ypart_, float* __restrict__ Y_,
               size_t wsStrideB, size_t outStrideF) {
    const int z = blockIdx.z;
    const float* Ypart = (const float*)((const char*)Ypart_ + (size_t)z * wsStrideB);
    float* Y = Y_ + (size_t)z * outStrideF;
    const size_t i = ((size_t)blockIdx.x * 256 + threadIdx.x) * 4;
    f32x4 s = *(const f32x4*)(Ypart + i);
    #pragma unroll
    for (int sl = 1; sl < 4; ++sl)
        s += *(const f32x4*)(Ypart + (size_t)sl * LDIM * CDIM + i);
    *(f32x4*)(Y + i) = s;
}

extern "C" void kernel_launch(void* const* d_in, const int* in_sizes, int n_in,
                              void* d_out, int out_size, void* d_ws, size_t ws_size,
                              hipStream_t stream) {
    const float* x1 = (const float*)d_in[0];
    const float* x2 = (const float*)d_in[1];
    float* out = (float*)d_out;

    const size_t MATB = (size_t)LDIM * LDIM * sizeof(float);   // 64 MB
    const size_t HMATB = MATB / 2;                             // 32 MB (fp16 mat)
    const size_t SMALLB = (size_t)64 * 1024;
    const size_t SLICE = HMATB + HMATB + (size_t)LDIM * CDIM * sizeof(__hip_bfloat16) + SMALLB;

    const int B = in_sizes[0] / (LDIM * CDIM);
    const size_t inStrideF = (size_t)LDIM * CDIM;
    const bool concurrent = ((size_t)B * SLICE <= ws_size);

    // no d_out memset needed — k_yreduce overwrites Y entirely.

    const int NB = concurrent ? B : 1;         // grid.z
    const int NL = concurrent ? 1 : B;         // host loop count
    const size_t wsStrideB = concurrent ? SLICE : 0;

    for (int b = 0; b < NL; ++b) {
        char* ws = (char*)d_ws;
        _Float16* Dsh = (_Float16*)ws;                       // buf1: Ds16 -> Ps16 -> Ypart
        _Float16* Psh = (_Float16*)ws;
        float* Ypart = (float*)ws;                           // 8MB, after att2
        char* buf2c = ws + HMATB;                            // 33 MB multi-use
        _Float16* Gh = (_Float16*)buf2c;                     // 32 MB
        __hip_bfloat16* X2h = (__hip_bfloat16*)buf2c;                    // 1 MB
        __hip_bfloat16* X2l = (__hip_bfloat16*)(buf2c + (size_t)LDIM * CDIM * 2);
        __hip_bfloat16* A2b = (__hip_bfloat16*)buf2c;                    // 32 MB
        __hip_bfloat16* X1T = (__hip_bfloat16*)(buf2c + HMATB);          // 1 MB
        float* pmz = (float*)(buf2c + HMATB);   // 128KB scratch, dead before x1t
        float* invn  = (float*)(ws + HMATB + HMATB + (size_t)LDIM * CDIM * sizeof(__hip_bfloat16));
        float* rowm  = invn + LDIM;   // unused (kept for layout stability)
        float* rowrz = rowm + LDIM;   // unused
        float* pixn  = rowrz + LDIM;

        const float* X2b_ = x2 + (size_t)b * inStrideF;
        const float* X1b_ = x1 + (size_t)b * inStrideF;
        float* Yb = out + (size_t)b * inStrideF;
        const size_t inS = concurrent ? inStrideF : 0;
        const size_t outS = concurrent ? inStrideF : 0;

        k_split     <<<dim3(LDIM * CDIM / 1024, 1, NB), 256, 0, stream>>>(X2b_, X2h, X2l, pixn, inS, wsStrideB);
        k_invnorm   <<<dim3(LDIM / 256, 1, NB), 256, 0, stream>>>(pixn, invn, wsStrideB);
        k_gemm_d    <<<dim3(LDIM / 128, LDIM / 128, NB), 256, 0, stream>>>(X2h, X2l, Dsh, wsStrideB);
        k_gdiag     <<<dim3(LDIM / 1024, LDIM / 8, NB), 256, 0, stream>>>(Dsh, Gh, wsStrideB);
        k_pool_stats<<<dim3(LDIM / 8, 4, NB), 256, 0, stream>>>(Gh, invn, Psh, pmz, wsStrideB);
        k_att2      <<<dim3(LDIM / 1024, LDIM / 8, NB), 256, 0, stream>>>(Psh, pmz, A2b, wsStrideB);
        k_x1t       <<<dim3(LDIM / 32, 1, NB), 256, 0, stream>>>(X1b_, X1T, inS, wsStrideB);
        k_gemm_y    <<<dim3(LDIM / 128, 4, NB), 256, 0, stream>>>(A2b, X1T, Ypart, wsStrideB);
        k_yreduce   <<<dim3(LDIM * CDIM / 1024, 1, NB), 256, 0, stream>>>(Ypart, Yb, wsStrideB, outS);
    }
}

// Round 17
// 340.148 us; speedup vs baseline: 1.2692x; 1.0740x over previous
//
#include <hip/hip_runtime.h>
#include <hip/hip_bf16.h>
#include <math.h>

// AtnConv (contextual attention) B=2, H=W=64, C=128, k=3.
// R17: EXACT R14 champion restored (measured 340.6us). R16's att2-inline
// stats merge REGRESSED (+25us: 4-way merge recomputed per row per block,
// ~0.7M redundant exp chains >> one 16-block combine launch). Separate
// k_stats_combine + x1t-then-att2 order restored.
// Pipeline: Ds = skewed X2·X2^T (split-bf16 MFMA, fp16, Ds[r][(c-r)&4095]);
// invn from exact fp32 pixnorm (fused in split); G = 9-tap diag stencil
// (vertical fp16 reads, XCD-band swizzle); Ps = pooled logits (skewed fp16,
// rounded BEFORE stats) + partial softmax stats (blockIdx.y=ch, wave
// butterfly) -> k_stats_combine; A2 = diag stencil of softmax(Ps) (bf16);
// Y = A2 @ X1 bf16 MFMA split-K=4 partials -> k_yreduce. Batch-concurrent
// grids (z=batch).
// Per-slice ws: buf1 [0,32MB) Ds16->Ps16->Ypart(8MB); buf2 [32,64MB):
// X2h/X2l -> G16 -> A2bf; X1T/pmz at +64MB; smalls at +65MB. SLICE=65MB+64KB.
// Lessons: R1 coalescing/R2 DRAM tiling/R7 nt/R13 unskew: neutral/worse.
// R3/R4 fusion loses (LDS). R11+R15 gemm_d re-tiling loses both directions
// (perf tracks MFMA-per-load amortization, not occupancy). R16 att2-inline
// stats loses. R8 XCD swizzle +28. R9 fp16 +53. R10 pool split +38.
// R12 de-atomic +17. R14 fuse/splitK4 +4.

constexpr int Hh = 64;
constexpr int Ww = 64;
constexpr int CDIM = 128;
constexpr int LDIM = Hh * Ww;   // 4096

typedef __attribute__((ext_vector_type(8))) short bf16x8;
typedef __attribute__((ext_vector_type(4))) float f32x4;
typedef __attribute__((ext_vector_type(4))) _Float16 f16x4;

// ---- split X2 into bf16 hi/lo parts + fused pixnorm (row sum of squares)
__global__ __launch_bounds__(256)
void k_split(const float* __restrict__ X, __hip_bfloat16* __restrict__ Xh_,
             __hip_bfloat16* __restrict__ Xl_, float* __restrict__ pixn_,
             size_t inStrideF, size_t wsStrideB) {
    const int z = blockIdx.z;
    const float* Xb = X + (size_t)z * inStrideF;
    __hip_bfloat16* Xh = (__hip_bfloat16*)((char*)Xh_ + (size_t)z * wsStrideB);
    __hip_bfloat16* Xl = (__hip_bfloat16*)((char*)Xl_ + (size_t)z * wsStrideB);
    float* pixn = (float*)((char*)pixn_ + (size_t)z * wsStrideB);
    const int i = (blockIdx.x * 256 + threadIdx.x) * 4;
    const float4 v = *(const float4*)(Xb + i);
    __hip_bfloat16 h[4], l[4];
    const float f[4] = {v.x, v.y, v.z, v.w};
    #pragma unroll
    for (int j = 0; j < 4; ++j) {
        h[j] = __float2bfloat16(f[j]);
        l[j] = __float2bfloat16(f[j] - __bfloat162float(h[j]));
    }
    *(ushort4*)(Xh + i) = *(ushort4*)h;
    *(ushort4*)(Xl + i) = *(ushort4*)l;
    // fused pixnorm: 32 lanes cover one 128-col row (4 elems/lane)
    float s = v.x * v.x + v.y * v.y + v.z * v.z + v.w * v.w;
    s += __shfl_xor(s, 1);
    s += __shfl_xor(s, 2);
    s += __shfl_xor(s, 4);
    s += __shfl_xor(s, 8);
    s += __shfl_xor(s, 16);
    if ((threadIdx.x & 31) == 0) pixn[i >> 7] = s;
}

// ---------------- invn[l] = 1/max(sqrt(sum 9-neigh pixn),eps)
__global__ void k_invnorm(const float* __restrict__ pixn_, float* __restrict__ invn_,
                          size_t wsStrideB) {
    const int z = blockIdx.z;
    const float* pixn = (const float*)((const char*)pixn_ + (size_t)z * wsStrideB);
    float* invn = (float*)((char*)invn_ + (size_t)z * wsStrideB);
    const int l = blockIdx.x * 256 + threadIdx.x;
    const int ly = l >> 6, lx = l & 63;
    float s = 0.f;
    #pragma unroll
    for (int ty = -1; ty <= 1; ++ty)
        #pragma unroll
        for (int tx = -1; tx <= 1; ++tx) {
            if ((unsigned)(ly + ty) < 64u && (unsigned)(lx + tx) < 64u)
                s += pixn[l + ty * Ww + tx];
        }
    invn[l] = 1.0f / fmaxf(sqrtf(s), 1e-4f);
}

// -------- Ds = skewed X2·X2^T via 3-term split-bf16 MFMA; fp16 store.
// 256 threads, 4 waves, 2x8 register tile (R11/R15: do not re-tile).
__global__ __launch_bounds__(256)
void k_gemm_d(const __hip_bfloat16* __restrict__ Xh_,
              const __hip_bfloat16* __restrict__ Xl_, _Float16* __restrict__ Ds_,
              size_t wsStrideB) {
    const int z = blockIdx.z;
    const __hip_bfloat16* Xh = (const __hip_bfloat16*)((const char*)Xh_ + (size_t)z * wsStrideB);
    const __hip_bfloat16* Xl = (const __hip_bfloat16*)((const char*)Xl_ + (size_t)z * wsStrideB);
    _Float16* Ds = (_Float16*)((char*)Ds_ + (size_t)z * wsStrideB);
    const int t = threadIdx.x;
    const int wave = t >> 6, lane = t & 63;
    const int quad = lane >> 4, l16 = lane & 15;
    const int bm = blockIdx.x * 128 + wave * 32;
    const int bn = blockIdx.y * 128;
    f32x4 acc[2][8] = {};
    for (int k0 = 0; k0 < CDIM; k0 += 32) {
        const int kq = k0 + quad * 8;
        bf16x8 ah[2], al[2], bh[8], bl[8];
        #pragma unroll
        for (int mi = 0; mi < 2; ++mi) {
            const size_t r = (size_t)(bm + mi * 16 + l16) * CDIM + kq;
            ah[mi] = *(const bf16x8*)(Xh + r);
            al[mi] = *(const bf16x8*)(Xl + r);
        }
        #pragma unroll
        for (int nf = 0; nf < 8; ++nf) {
            const size_t r = (size_t)(bn + nf * 16 + l16) * CDIM + kq;
            bh[nf] = *(const bf16x8*)(Xh + r);
            bl[nf] = *(const bf16x8*)(Xl + r);
        }
        #pragma unroll
        for (int mi = 0; mi < 2; ++mi)
            #pragma unroll
            for (int nf = 0; nf < 8; ++nf) {
                acc[mi][nf] = __builtin_amdgcn_mfma_f32_16x16x32_bf16(ah[mi], bh[nf], acc[mi][nf], 0, 0, 0);
                acc[mi][nf] = __builtin_amdgcn_mfma_f32_16x16x32_bf16(ah[mi], bl[nf], acc[mi][nf], 0, 0, 0);
                acc[mi][nf] = __builtin_amdgcn_mfma_f32_16x16x32_bf16(al[mi], bh[nf], acc[mi][nf], 0, 0, 0);
            }
    }
    #pragma unroll
    for (int mi = 0; mi < 2; ++mi)
        #pragma unroll
        for (int nf = 0; nf < 8; ++nf) {
            const int row = bm + mi * 16 + quad * 4;
            const int col = bn + nf * 16 + l16;
            #pragma unroll
            for (int r = 0; r < 4; ++r)
                Ds[(size_t)(row + r) * LDIM + ((col - row - r) & (LDIM - 1))] =
                    (_Float16)acc[mi][nf][r];
        }
}

// ---- G[x,l] = sum_t D[x+t,l+t] read vertically from skewed fp16 Ds.
// XCD-band swizzle. Thread: 4 diagonals x T=8 rows; f16x4 loads, fp16 store.
__global__ __launch_bounds__(256)
void k_gdiag(const _Float16* __restrict__ Ds_, _Float16* __restrict__ G_,
             size_t wsStrideB) {
    const int z = blockIdx.z;
    const _Float16* Ds = (const _Float16*)((const char*)Ds_ + (size_t)z * wsStrideB);
    _Float16* G = (_Float16*)((char*)G_ + (size_t)z * wsStrideB);
    constexpr int T = 8;
    const int f = blockIdx.x + gridDim.x * blockIdx.y;
    const int swz = (f & 7) * 256 + (f >> 3);
    const int d0 = ((swz & 3) * 256 + threadIdx.x) * 4;
    const int x0 = (swz >> 2) * T;
    const int xyc = x0 >> 6;
    const int xxb = x0 & 63;
    float acc[T][4] = {};
    #pragma unroll
    for (int c = 0; c < 3; ++c) {
        const int bc = c * 64 - 65;          // -65, -1, 63
        const int ty = c - 1;
        if ((unsigned)(xyc + ty) >= 64u) continue;
        float w[T + 2][4];
        #pragma unroll
        for (int u = 0; u < T + 2; ++u) {
            const int r = x0 + bc + u;
            if ((unsigned)r < (unsigned)LDIM) {
                const f16x4 v = *(const f16x4*)(Ds + (size_t)r * LDIM + d0);
                w[u][0] = (float)v.x; w[u][1] = (float)v.y;
                w[u][2] = (float)v.z; w[u][3] = (float)v.w;
            } else {
                w[u][0] = w[u][1] = w[u][2] = w[u][3] = 0.f;
            }
        }
        #pragma unroll
        for (int i = 0; i < T; ++i) {
            const int px = xxb + i;
            const int p  = x0 + i;
            #pragma unroll
            for (int j = 0; j < 4; ++j) {
                const int l  = (p + d0 + j) & (LDIM - 1);
                const int ly = l >> 6, lx = l & 63;
                if ((unsigned)(ly + ty) < 64u) {
                    float s = acc[i][j];
                    if (px > 0 && lx > 0)   s += w[i][j];
                    s += w[i + 1][j];
                    if (px < 63 && lx < 63) s += w[i + 2][j];
                    acc[i][j] = s;
                }
            }
        }
    }
    #pragma unroll
    for (int i = 0; i < T; ++i) {
        const int x = x0 + i;
        const int l0i = (x + d0) & (LDIM - 1);
        union { _Float16 h[4]; unsigned short us[4]; unsigned int ui[2]; } cv;
        #pragma unroll
        for (int j = 0; j < 4; ++j) cv.h[j] = (_Float16)acc[i][j];
        unsigned short* bp = (unsigned short*)(G + (size_t)x * LDIM);
        if (l0i <= LDIM - 4) {
            if (!(l0i & 1)) {
                *(unsigned int*)(bp + l0i)     = cv.ui[0];
                *(unsigned int*)(bp + l0i + 2) = cv.ui[1];
            } else {
                bp[l0i] = cv.us[0];
                *(unsigned int*)(bp + l0i + 1) =
                    (unsigned int)cv.us[1] | ((unsigned int)cv.us[2] << 16);
                bp[l0i + 3] = cv.us[3];
            }
        } else {
            #pragma unroll
            for (int j = 0; j < 4; ++j)
                bp[(l0i + j) & (LDIM - 1)] = cv.us[j];
        }
    }
}

// ------- P[x,l] = (90/cnt)*invn[l]*sum_s G[x+s,l]; one 1024-col chunk per
// block (blockIdx.y = ch). P rounded to fp16 BEFORE stats. Skewed fp16 store.
// Per-(row,ch) partial (m,Z) via wave shfl butterfly -> pmz scratch.
// XCD-band swizzle on blockIdx.x.
__global__ __launch_bounds__(256)
void k_pool_stats(const _Float16* __restrict__ G_, const float* __restrict__ invn_,
                  _Float16* __restrict__ Ps_, float* __restrict__ pmz_,
                  size_t wsStrideB) {
    const int z = blockIdx.z;
    const _Float16* G = (const _Float16*)((const char*)G_ + (size_t)z * wsStrideB);
    const float* invn = (const float*)((const char*)invn_ + (size_t)z * wsStrideB);
    _Float16* Ps = (_Float16*)((char*)Ps_ + (size_t)z * wsStrideB);
    float* pmz = (float*)((char*)pmz_ + (size_t)z * wsStrideB);
    constexpr int T = 8;
    const int f = blockIdx.x;                    // 512 x-blocks
    const int swz = (f & 7) * 64 + (f >> 3);     // XCD k: x0 in [k*512,(k+1)*512)
    const int x0 = swz * T;
    const int ch = blockIdx.y;                   // 1024-col chunk
    const int t  = threadIdx.x;
    const int wave = t >> 6, lane = t & 63;
    const int xyc = x0 >> 6;
    const int xxb = x0 & 63;
    const int cy = 1 + (xyc > 0) + (xyc < 63);
    float sc[T];
    #pragma unroll
    for (int i = 0; i < T; ++i) {
        const int xx = xxb + i;
        sc[i] = 90.0f / (float)(cy * (1 + (xx > 0) + (xx < 63)));
    }
    float m[T], Z[T];

    const int l0 = ch * 1024 + t * 4;
    const f32x4 inl = *(const f32x4*)(invn + l0);
    f32x4 acc[T];
    #pragma unroll
    for (int i = 0; i < T; ++i) acc[i] = (f32x4){0.f, 0.f, 0.f, 0.f};
    #pragma unroll
    for (int c = 0; c < 3; ++c) {
        const int bc = c * 64 - 65;
        const int ty = c - 1;
        if ((unsigned)(xyc + ty) >= 64u) continue;
        f32x4 w[T + 2];
        #pragma unroll
        for (int u = 0; u < T + 2; ++u) {
            const int r = x0 + bc + u;
            if ((unsigned)r < (unsigned)LDIM) {
                const f16x4 v = *(const f16x4*)(G + (size_t)r * LDIM + l0);
                w[u] = (f32x4){(float)v.x, (float)v.y, (float)v.z, (float)v.w};
            } else {
                w[u] = (f32x4){0.f, 0.f, 0.f, 0.f};
            }
        }
        #pragma unroll
        for (int i = 0; i < T; ++i) {
            const int xx = xxb + i;
            if (xx > 0)  acc[i] += w[i];
            acc[i] += w[i + 1];
            if (xx < 63) acc[i] += w[i + 2];
        }
    }
    #pragma unroll
    for (int i = 0; i < T; ++i) {
        const f32x4 p = acc[i] * sc[i] * inl;
        const int x = x0 + i;
        const int c0 = (l0 - x) & (LDIM - 1);
        union { _Float16 h[4]; unsigned short us[4]; unsigned int ui[2]; } cv;
        float pr[4];
        #pragma unroll
        for (int j = 0; j < 4; ++j) {
            cv.h[j] = (_Float16)p[j];
            pr[j] = (float)cv.h[j];
        }
        unsigned short* bp = (unsigned short*)(Ps + (size_t)x * LDIM);
        if (c0 <= LDIM - 4) {
            if (!(c0 & 1)) {
                *(unsigned int*)(bp + c0)     = cv.ui[0];
                *(unsigned int*)(bp + c0 + 2) = cv.ui[1];
            } else {
                bp[c0] = cv.us[0];
                *(unsigned int*)(bp + c0 + 1) =
                    (unsigned int)cv.us[1] | ((unsigned int)cv.us[2] << 16);
                bp[c0 + 3] = cv.us[3];
            }
        } else {
            #pragma unroll
            for (int j = 0; j < 4; ++j)
                bp[(c0 + j) & (LDIM - 1)] = cv.us[j];
        }
        const float mx = fmaxf(fmaxf(pr[0], pr[1]), fmaxf(pr[2], pr[3]));
        m[i] = mx;
        Z[i] = __expf(pr[0] - mx) + __expf(pr[1] - mx)
             + __expf(pr[2] - mx) + __expf(pr[3] - mx);
    }
    // wave butterfly reduction of (m,Z) per row, then 4-wave combine via LDS
    __shared__ float sm[4][T], sz[4][T];
    #pragma unroll
    for (int i = 0; i < T; ++i) {
        float mi = m[i], zi = Z[i];
        #pragma unroll
        for (int s = 1; s < 64; s <<= 1) {
            const float m2 = __shfl_xor(mi, s);
            const float z2 = __shfl_xor(zi, s);
            const float nm = fmaxf(mi, m2);
            zi = zi * __expf(mi - nm) + z2 * __expf(m2 - nm);
            mi = nm;
        }
        if (lane == 0) { sm[wave][i] = mi; sz[wave][i] = zi; }
    }
    __syncthreads();
    if (t < T) {
        float mi = sm[0][t], zi = sz[0][t];
        #pragma unroll
        for (int wv = 1; wv < 4; ++wv) {
            const float m2 = sm[wv][t], z2 = sz[wv][t];
            const float nm = fmaxf(mi, m2);
            zi = zi * __expf(mi - nm) + z2 * __expf(m2 - nm);
            mi = nm;
        }
        pmz[(size_t)ch * LDIM + x0 + t] = mi;                    // partial max
        pmz[(size_t)(4 + ch) * LDIM + x0 + t] = zi;              // partial Z
    }
}

// ---- merge 4 channel-partials -> rowm, rowrz. 16 blocks x 256.
__global__ __launch_bounds__(256)
void k_stats_combine(const float* __restrict__ pmz_, float* __restrict__ rowm_,
                     float* __restrict__ rowrz_, size_t wsStrideB) {
    const int z = blockIdx.z;
    const float* pmz = (const float*)((const char*)pmz_ + (size_t)z * wsStrideB);
    float* rowm = (float*)((char*)rowm_ + (size_t)z * wsStrideB);
    float* rowrz = (float*)((char*)rowrz_ + (size_t)z * wsStrideB);
    const int l = blockIdx.x * 256 + threadIdx.x;
    float mi = pmz[l], zi = pmz[(size_t)4 * LDIM + l];
    #pragma unroll
    for (int ch = 1; ch < 4; ++ch) {
        const float m2 = pmz[(size_t)ch * LDIM + l];
        const float z2 = pmz[(size_t)(4 + ch) * LDIM + l];
        const float nm = fmaxf(mi, m2);
        zi = zi * __expf(mi - nm) + z2 * __expf(m2 - nm);
        mi = nm;
    }
    rowm[l] = mi;
    rowrz[l] = 1.0f / zi;
}

// ---- X1 [4096][128] fp32 -> X1T [128][4096] bf16 (LDS-tiled transpose)
// Runs AFTER k_stats_combine: X1T region doubles as pmz scratch before this.
__global__ __launch_bounds__(256)
void k_x1t(const float* __restrict__ X1, __hip_bfloat16* __restrict__ X1T_,
           size_t inStrideF, size_t wsStrideB) {
    const int z = blockIdx.z;
    const float* X1b = X1 + (size_t)z * inStrideF;
    __hip_bfloat16* X1T = (__hip_bfloat16*)((char*)X1T_ + (size_t)z * wsStrideB);
    __shared__ float tile[32][132];
    const int k0 = blockIdx.x * 32;
    const int t  = threadIdx.x;
    const int kr = t >> 3;
    const int c0 = (t & 7) * 16;
    #pragma unroll
    for (int j = 0; j < 4; ++j) {
        const float4 v = *(const float4*)(X1b + (size_t)(k0 + kr) * CDIM + c0 + 4 * j);
        tile[kr][c0 + 4 * j + 0] = v.x;
        tile[kr][c0 + 4 * j + 1] = v.y;
        tile[kr][c0 + 4 * j + 2] = v.z;
        tile[kr][c0 + 4 * j + 3] = v.w;
    }
    __syncthreads();
    const int c  = t >> 1;
    const int kh = (t & 1) * 16;
    __hip_bfloat16 outv[16];
    #pragma unroll
    for (int j = 0; j < 16; ++j)
        outv[j] = __float2bfloat16(tile[kh + j][c]);
    *(ushort4*)(X1T + (size_t)c * LDIM + k0 + kh)      = *(ushort4*)(outv);
    *(ushort4*)(X1T + (size_t)c * LDIM + k0 + kh + 4)  = *(ushort4*)(outv + 4);
    *(ushort4*)(X1T + (size_t)c * LDIM + k0 + kh + 8)  = *(ushort4*)(outv + 8);
    *(ushort4*)(X1T + (size_t)c * LDIM + k0 + kh + 12) = *(ushort4*)(outv + 12);
}

// ---- A2[p,q] = sum_t exp(P[p+t,q+t]-m)*rz. Reads skewed fp16 Ps vertically.
// XCD-band swizzle matches k_pool_stats' write bands.
__global__ __launch_bounds__(256)
void k_att2(const _Float16* __restrict__ Ps_, const float* __restrict__ rowm_,
            const float* __restrict__ rowrz_, __hip_bfloat16* __restrict__ A2_,
            size_t wsStrideB) {
    const int z = blockIdx.z;
    const _Float16* Ps = (const _Float16*)((const char*)Ps_ + (size_t)z * wsStrideB);
    const float* rowm = (const float*)((const char*)rowm_ + (size_t)z * wsStrideB);
    const float* rowrz = (const float*)((const char*)rowrz_ + (size_t)z * wsStrideB);
    __hip_bfloat16* A2 = (__hip_bfloat16*)((char*)A2_ + (size_t)z * wsStrideB);
    constexpr int T = 8;
    const int f = blockIdx.x + gridDim.x * blockIdx.y;
    const int swz = (f & 7) * 256 + (f >> 3);
    const int d0 = ((swz & 3) * 256 + threadIdx.x) * 4;
    const int p0 = (swz >> 2) * T;
    const int pyc = p0 >> 6;
    const int pxb = p0 & 63;
    float acc[T][4] = {};
    #pragma unroll
    for (int c = 0; c < 3; ++c) {
        const int bc = c * 64 - 65;          // -65, -1, 63
        const int ty = c - 1;
        if ((unsigned)(pyc + ty) >= 64u) continue;
        float e[T + 2][4];
        #pragma unroll
        for (int u = 0; u < T + 2; ++u) {
            const int r = p0 + bc + u;
            if ((unsigned)r < (unsigned)LDIM) {
                const f16x4 w = *(const f16x4*)(Ps + (size_t)r * LDIM + d0);
                const float mr = rowm[r], rzr = rowrz[r];
                e[u][0] = __expf((float)w.x - mr) * rzr;
                e[u][1] = __expf((float)w.y - mr) * rzr;
                e[u][2] = __expf((float)w.z - mr) * rzr;
                e[u][3] = __expf((float)w.w - mr) * rzr;
            } else {
                e[u][0] = e[u][1] = e[u][2] = e[u][3] = 0.f;
            }
        }
        #pragma unroll
        for (int i = 0; i < T; ++i) {
            const int px = pxb + i;
            const int p  = p0 + i;
            #pragma unroll
            for (int j = 0; j < 4; ++j) {
                const int q  = (p + d0 + j) & (LDIM - 1);
                const int qy = q >> 6, qx = q & 63;
                if ((unsigned)(qy + ty) < 64u) {
                    float s = acc[i][j];
                    if (px > 0 && qx > 0)   s += e[i][j];
                    s += e[i + 1][j];
                    if (px < 63 && qx < 63) s += e[i + 2][j];
                    acc[i][j] = s;
                }
            }
        }
    }
    #pragma unroll
    for (int i = 0; i < T; ++i) {
        const int p = p0 + i;
        const int q0i = (p + d0) & (LDIM - 1);
        union { __hip_bfloat16 h[4]; unsigned short us[4]; unsigned int ui[2]; } cv;
        #pragma unroll
        for (int j = 0; j < 4; ++j) cv.h[j] = __float2bfloat16(acc[i][j]);
        unsigned short* bp = (unsigned short*)(A2 + (size_t)p * LDIM);
        if (q0i <= LDIM - 4) {
            if (!(q0i & 1)) {
                *(unsigned int*)(bp + q0i)     = cv.ui[0];
                *(unsigned int*)(bp + q0i + 2) = cv.ui[1];
            } else {
                bp[q0i] = cv.us[0];
                *(unsigned int*)(bp + q0i + 1) =
                    (unsigned int)cv.us[1] | ((unsigned int)cv.us[2] << 16);
                bp[q0i + 3] = cv.us[3];
            }
        } else {
            #pragma unroll
            for (int j = 0; j < 4; ++j)
                bp[(q0i + j) & (LDIM - 1)] = cv.us[j];
        }
    }
}

// ---------- Ypart[slice] = A2[.,kc:kc+1024] @ X1T[.,kc:kc+1024]^T (split-K=4)
__global__ __launch_bounds__(256)
void k_gemm_y(const __hip_bfloat16* __restrict__ A2b_,
              const __hip_bfloat16* __restrict__ X1T_, float* __restrict__ Ypart_,
              size_t wsStrideB) {
    const int z = blockIdx.z;
    const __hip_bfloat16* A2b = (const __hip_bfloat16*)((const char*)A2b_ + (size_t)z * wsStrideB);
    const __hip_bfloat16* X1T = (const __hip_bfloat16*)((const char*)X1T_ + (size_t)z * wsStrideB);
    float* Ypart = (float*)((char*)Ypart_ + (size_t)z * wsStrideB)
                 + (size_t)blockIdx.y * LDIM * CDIM;
    const int t = threadIdx.x;
    const int wave = t >> 6, lane = t & 63;
    const int quad = lane >> 4, l16 = lane & 15;
    const int bm = blockIdx.x * 128 + wave * 32;
    const int kc = blockIdx.y * 1024;
    f32x4 acc[2][8] = {};
    for (int ks = 0; ks < 1024; ks += 32) {
        const int kq = kc + ks + quad * 8;
        bf16x8 a[2], b[8];
        #pragma unroll
        for (int mi = 0; mi < 2; ++mi)
            a[mi] = *(const bf16x8*)(A2b + (size_t)(bm + mi * 16 + l16) * LDIM + kq);
        #pragma unroll
        for (int nf = 0; nf < 8; ++nf)
            b[nf] = *(const bf16x8*)(X1T + (size_t)(nf * 16 + l16) * LDIM + kq);
        #pragma unroll
        for (int mi = 0; mi < 2; ++mi)
            #pragma unroll
            for (int nf = 0; nf < 8; ++nf)
                acc[mi][nf] = __builtin_amdgcn_mfma_f32_16x16x32_bf16(a[mi], b[nf], acc[mi][nf], 0, 0, 0);
    }
    #pragma unroll
    for (int mi = 0; mi < 2; ++mi)
        #pragma unroll
        for (int nf = 0; nf < 8; ++nf)
            #pragma unroll
            for (int r = 0; r < 4; ++r)
                Ypart[(size_t)(bm + mi * 16 + quad * 4 + r) * CDIM + nf * 16 + l16] =
                    acc[mi][nf][r];
}

// ---------- Y = sum of 4 K-slices of Ypart (float4 streams)
__global__ __launch_bounds__(256)
void k_yreduce(const float* __restrict__ Ypart_, float* __restrict__ Y_,
               size_t wsStrideB, size_t outStrideF) {
    const int z = blockIdx.z;
    const float* Ypart = (const float*)((const char*)Ypart_ + (size_t)z * wsStrideB);
    float* Y = Y_ + (size_t)z * outStrideF;
    const size_t i = ((size_t)blockIdx.x * 256 + threadIdx.x) * 4;
    f32x4 s = *(const f32x4*)(Ypart + i);
    #pragma unroll
    for (int sl = 1; sl < 4; ++sl)
        s += *(const f32x4*)(Ypart + (size_t)sl * LDIM * CDIM + i);
    *(f32x4*)(Y + i) = s;
}

extern "C" void kernel_launch(void* const* d_in, const int* in_sizes, int n_in,
                              void* d_out, int out_size, void* d_ws, size_t ws_size,
                              hipStream_t stream) {
    const float* x1 = (const float*)d_in[0];
    const float* x2 = (const float*)d_in[1];
    float* out = (float*)d_out;

    const size_t MATB = (size_t)LDIM * LDIM * sizeof(float);   // 64 MB
    const size_t HMATB = MATB / 2;                             // 32 MB (fp16 mat)
    const size_t SMALLB = (size_t)64 * 1024;
    const size_t SLICE = HMATB + HMATB + (size_t)LDIM * CDIM * sizeof(__hip_bfloat16) + SMALLB;

    const int B = in_sizes[0] / (LDIM * CDIM);
    const size_t inStrideF = (size_t)LDIM * CDIM;
    const bool concurrent = ((size_t)B * SLICE <= ws_size);

    // no d_out memset needed — k_yreduce overwrites Y entirely.

    const int NB = concurrent ? B : 1;         // grid.z
    const int NL = concurrent ? 1 : B;         // host loop count
    const size_t wsStrideB = concurrent ? SLICE : 0;

    for (int b = 0; b < NL; ++b) {
        char* ws = (char*)d_ws;
        _Float16* Dsh = (_Float16*)ws;                       // buf1: Ds16 -> Ps16 -> Ypart
        _Float16* Psh = (_Float16*)ws;
        float* Ypart = (float*)ws;                           // 8MB, after att2
        char* buf2c = ws + HMATB;                            // 33 MB multi-use
        _Float16* Gh = (_Float16*)buf2c;                     // 32 MB
        __hip_bfloat16* X2h = (__hip_bfloat16*)buf2c;                    // 1 MB
        __hip_bfloat16* X2l = (__hip_bfloat16*)(buf2c + (size_t)LDIM * CDIM * 2);
        __hip_bfloat16* A2b = (__hip_bfloat16*)buf2c;                    // 32 MB
        __hip_bfloat16* X1T = (__hip_bfloat16*)(buf2c + HMATB);          // 1 MB
        float* pmz = (float*)(buf2c + HMATB);   // 128KB scratch, dead before x1t
        float* invn  = (float*)(ws + HMATB + HMATB + (size_t)LDIM * CDIM * sizeof(__hip_bfloat16));
        float* rowm  = invn + LDIM;
        float* rowrz = rowm + LDIM;
        float* pixn  = rowrz + LDIM;

        const float* X2b_ = x2 + (size_t)b * inStrideF;
        const float* X1b_ = x1 + (size_t)b * inStrideF;
        float* Yb = out + (size_t)b * inStrideF;
        const size_t inS = concurrent ? inStrideF : 0;
        const size_t outS = concurrent ? inStrideF : 0;

        k_split        <<<dim3(LDIM * CDIM / 1024, 1, NB), 256, 0, stream>>>(X2b_, X2h, X2l, pixn, inS, wsStrideB);
        k_invnorm      <<<dim3(LDIM / 256, 1, NB), 256, 0, stream>>>(pixn, invn, wsStrideB);
        k_gemm_d       <<<dim3(LDIM / 128, LDIM / 128, NB), 256, 0, stream>>>(X2h, X2l, Dsh, wsStrideB);
        k_gdiag        <<<dim3(LDIM / 1024, LDIM / 8, NB), 256, 0, stream>>>(Dsh, Gh, wsStrideB);
        k_pool_stats   <<<dim3(LDIM / 8, 4, NB), 256, 0, stream>>>(Gh, invn, Psh, pmz, wsStrideB);
        k_stats_combine<<<dim3(LDIM / 256, 1, NB), 256, 0, stream>>>(pmz, rowm, rowrz, wsStrideB);
        k_x1t          <<<dim3(LDIM / 32, 1, NB), 256, 0, stream>>>(X1b_, X1T, inS, wsStrideB);
        k_att2         <<<dim3(LDIM / 1024, LDIM / 8, NB), 256, 0, stream>>>(Psh, rowm, rowrz, A2b, wsStrideB);
        k_gemm_y       <<<dim3(LDIM / 128, 4, NB), 256, 0, stream>>>(A2b, X1T, Ypart, wsStrideB);
        k_yreduce      <<<dim3(LDIM * CDIM / 1024, 1, NB), 256, 0, stream>>>(Ypart, Yb, wsStrideB, outS);
    }
}